// Round 1
// baseline (586.234 us; speedup 1.0000x reference)
//
#include <hip/hip_runtime.h>
#include <cstddef>

// Problem constants
constexpr int DM   = 512;    // d_model
constexpr int DN   = 64;     // d_state
constexpr int SEQL = 4096;
constexpr int CH   = 128;            // chunks per sequence for parallel scan
constexpr int LCH  = SEQL / CH;      // 32 steps per chunk

// ---------------------------------------------------------------------------
// LayerNorm row stats: one wave (64 lanes) per row of 512.
// ---------------------------------------------------------------------------
__global__ __launch_bounds__(256) void k_lnstats(const float* __restrict__ X,
                                                 float* __restrict__ stats) {
    const int lane = threadIdx.x & 63;
    const int w    = threadIdx.x >> 6;
    const int row  = blockIdx.x * 4 + w;
    const float* xr = X + (size_t)row * DM;
    float4 v0 = *reinterpret_cast<const float4*>(&xr[lane * 8]);
    float4 v1 = *reinterpret_cast<const float4*>(&xr[lane * 8 + 4]);
    float s  = v0.x + v0.y + v0.z + v0.w + v1.x + v1.y + v1.z + v1.w;
    float s2 = v0.x*v0.x + v0.y*v0.y + v0.z*v0.z + v0.w*v0.w
             + v1.x*v1.x + v1.y*v1.y + v1.z*v1.z + v1.w*v1.w;
#pragma unroll
    for (int o = 32; o > 0; o >>= 1) {
        s  += __shfl_xor(s, o);
        s2 += __shfl_xor(s2, o);
    }
    if (lane == 0) {
        float mu  = s * (1.0f / DM);
        float var = s2 * (1.0f / DM) - mu * mu;   // ddof=0 like jnp.var
        stats[row * 2]     = mu;
        stats[row * 2 + 1] = rsqrtf(var + 1e-3f); // keras LN eps
    }
}

// ---------------------------------------------------------------------------
// GEMM1: U[M,512] = LayerNorm(X) @ W_in + b_in   (LN applied on-the-fly)
// 128x128 tile, BK=32, 256 threads, 8x8 per thread (2x2 blocks of 4x4).
// ---------------------------------------------------------------------------
__global__ __launch_bounds__(256) void k_gemm_in(
    const float* __restrict__ X, const float* __restrict__ stats,
    const float* __restrict__ gamma, const float* __restrict__ beta,
    const float* __restrict__ W, const float* __restrict__ bvec,
    float* __restrict__ U)
{
    constexpr int BM = 128, BN = 128, BK = 32;
    __shared__ float As[BK][BM + 4];
    __shared__ float Bs[BK][BN + 4];
    const int tid = threadIdx.x;
    const int m0 = blockIdx.y * BM;
    const int n0 = blockIdx.x * BN;
    const int tx = tid & 15, ty = tid >> 4;

    float acc[2][2][4][4];
#pragma unroll
    for (int a = 0; a < 2; a++)
#pragma unroll
      for (int b = 0; b < 2; b++)
#pragma unroll
        for (int i = 0; i < 4; i++)
#pragma unroll
          for (int j = 0; j < 4; j++) acc[a][b][i][j] = 0.f;

    for (int k0 = 0; k0 < DM; k0 += BK) {
        // A tile (with fused LayerNorm), stored transposed As[k][m]
#pragma unroll
        for (int j = 0; j < 4; j++) {
            int id = tid + j * 256;
            int r = id >> 3, c4 = id & 7;
            int gr = m0 + r, gc = k0 + c4 * 4;
            float4 v  = *reinterpret_cast<const float4*>(&X[(size_t)gr * DM + gc]);
            float mu = stats[gr * 2], rs = stats[gr * 2 + 1];
            float4 g  = *reinterpret_cast<const float4*>(&gamma[gc]);
            float4 bb = *reinterpret_cast<const float4*>(&beta[gc]);
            As[c4 * 4 + 0][r] = (v.x - mu) * rs * g.x + bb.x;
            As[c4 * 4 + 1][r] = (v.y - mu) * rs * g.y + bb.y;
            As[c4 * 4 + 2][r] = (v.z - mu) * rs * g.z + bb.z;
            As[c4 * 4 + 3][r] = (v.w - mu) * rs * g.w + bb.w;
        }
        // B tile
#pragma unroll
        for (int j = 0; j < 4; j++) {
            int id = tid + j * 256;
            int r = id >> 5, c4 = id & 31;
            float4 v = *reinterpret_cast<const float4*>(&W[(size_t)(k0 + r) * DM + n0 + c4 * 4]);
            *reinterpret_cast<float4*>(&Bs[r][c4 * 4]) = v;
        }
        __syncthreads();
#pragma unroll
        for (int k = 0; k < BK; k++) {
            float4 a0 = *reinterpret_cast<const float4*>(&As[k][ty * 4]);
            float4 a1 = *reinterpret_cast<const float4*>(&As[k][64 + ty * 4]);
            float4 b0 = *reinterpret_cast<const float4*>(&Bs[k][tx * 4]);
            float4 b1 = *reinterpret_cast<const float4*>(&Bs[k][64 + tx * 4]);
            float av[2][4] = {{a0.x, a0.y, a0.z, a0.w}, {a1.x, a1.y, a1.z, a1.w}};
            float bv[2][4] = {{b0.x, b0.y, b0.z, b0.w}, {b1.x, b1.y, b1.z, b1.w}};
#pragma unroll
            for (int a = 0; a < 2; a++)
#pragma unroll
              for (int b = 0; b < 2; b++)
#pragma unroll
                for (int i = 0; i < 4; i++)
#pragma unroll
                  for (int j = 0; j < 4; j++)
                    acc[a][b][i][j] = fmaf(av[a][i], bv[b][j], acc[a][b][i][j]);
        }
        __syncthreads();
    }
#pragma unroll
    for (int a = 0; a < 2; a++)
#pragma unroll
      for (int i = 0; i < 4; i++) {
        int gr = m0 + a * 64 + ty * 4 + i;
#pragma unroll
        for (int b = 0; b < 2; b++) {
          int gc = n0 + b * 64 + tx * 4;
          float4 bias = *reinterpret_cast<const float4*>(&bvec[gc]);
          float4 o;
          o.x = acc[a][b][i][0] + bias.x;
          o.y = acc[a][b][i][1] + bias.y;
          o.z = acc[a][b][i][2] + bias.z;
          o.w = acc[a][b][i][3] + bias.w;
          *reinterpret_cast<float4*>(&U[(size_t)gr * DM + gc]) = o;
        }
      }
}

// ---------------------------------------------------------------------------
// GEMM2: xs = U@W_xs, Bm = U@W_B + b_B, Cm = U@W_C + b_C  (A read once)
// Writes Bu = Bm*xs and Cc = Cm.  128 rows x 64 cols per block.
// ---------------------------------------------------------------------------
__global__ __launch_bounds__(256) void k_gemm_bcx(
    const float* __restrict__ U,
    const float* __restrict__ Wxs, const float* __restrict__ Wb,
    const float* __restrict__ bB, const float* __restrict__ Wc,
    const float* __restrict__ bC,
    float* __restrict__ Bu, float* __restrict__ Cc)
{
    constexpr int BM = 128, BK = 32;
    __shared__ float As[BK][BM + 4];
    __shared__ float Bs[3][BK][DN + 4];
    const int tid = threadIdx.x;
    const int m0 = blockIdx.x * BM;
    const int tx = tid & 15, ty = tid >> 4;

    float aX[2][4][4], aB[2][4][4], aC[2][4][4];
#pragma unroll
    for (int a = 0; a < 2; a++)
#pragma unroll
      for (int i = 0; i < 4; i++)
#pragma unroll
        for (int j = 0; j < 4; j++) { aX[a][i][j] = 0.f; aB[a][i][j] = 0.f; aC[a][i][j] = 0.f; }

    for (int k0 = 0; k0 < DM; k0 += BK) {
#pragma unroll
        for (int j = 0; j < 4; j++) {
            int id = tid + j * 256;
            int r = id >> 3, c4 = id & 7;
            float4 v = *reinterpret_cast<const float4*>(&U[(size_t)(m0 + r) * DM + k0 + c4 * 4]);
            As[c4 * 4 + 0][r] = v.x;
            As[c4 * 4 + 1][r] = v.y;
            As[c4 * 4 + 2][r] = v.z;
            As[c4 * 4 + 3][r] = v.w;
        }
#pragma unroll
        for (int j = 0; j < 2; j++) {
            int id = tid + j * 256;
            int r = id >> 4, c4 = id & 15;
            *reinterpret_cast<float4*>(&Bs[0][r][c4 * 4]) =
                *reinterpret_cast<const float4*>(&Wxs[(size_t)(k0 + r) * DN + c4 * 4]);
            *reinterpret_cast<float4*>(&Bs[1][r][c4 * 4]) =
                *reinterpret_cast<const float4*>(&Wb[(size_t)(k0 + r) * DN + c4 * 4]);
            *reinterpret_cast<float4*>(&Bs[2][r][c4 * 4]) =
                *reinterpret_cast<const float4*>(&Wc[(size_t)(k0 + r) * DN + c4 * 4]);
        }
        __syncthreads();
#pragma unroll
        for (int k = 0; k < BK; k++) {
            float4 a0 = *reinterpret_cast<const float4*>(&As[k][ty * 4]);
            float4 a1 = *reinterpret_cast<const float4*>(&As[k][64 + ty * 4]);
            float4 bx = *reinterpret_cast<const float4*>(&Bs[0][k][tx * 4]);
            float4 bb = *reinterpret_cast<const float4*>(&Bs[1][k][tx * 4]);
            float4 bc = *reinterpret_cast<const float4*>(&Bs[2][k][tx * 4]);
            float av[2][4] = {{a0.x, a0.y, a0.z, a0.w}, {a1.x, a1.y, a1.z, a1.w}};
            float xv[4] = {bx.x, bx.y, bx.z, bx.w};
            float bv[4] = {bb.x, bb.y, bb.z, bb.w};
            float cv[4] = {bc.x, bc.y, bc.z, bc.w};
#pragma unroll
            for (int a = 0; a < 2; a++)
#pragma unroll
              for (int i = 0; i < 4; i++)
#pragma unroll
                for (int j = 0; j < 4; j++) {
                    aX[a][i][j] = fmaf(av[a][i], xv[j], aX[a][i][j]);
                    aB[a][i][j] = fmaf(av[a][i], bv[j], aB[a][i][j]);
                    aC[a][i][j] = fmaf(av[a][i], cv[j], aC[a][i][j]);
                }
        }
        __syncthreads();
    }
#pragma unroll
    for (int a = 0; a < 2; a++)
#pragma unroll
      for (int i = 0; i < 4; i++) {
        int gr = m0 + a * 64 + ty * 4 + i;
        int gc = tx * 4;
        float4 bBv = *reinterpret_cast<const float4*>(&bB[gc]);
        float4 bCv = *reinterpret_cast<const float4*>(&bC[gc]);
        float4 obu, oc;
        obu.x = (aB[a][i][0] + bBv.x) * aX[a][i][0];
        obu.y = (aB[a][i][1] + bBv.y) * aX[a][i][1];
        obu.z = (aB[a][i][2] + bBv.z) * aX[a][i][2];
        obu.w = (aB[a][i][3] + bBv.w) * aX[a][i][3];
        oc.x = aC[a][i][0] + bCv.x;
        oc.y = aC[a][i][1] + bCv.y;
        oc.z = aC[a][i][2] + bCv.z;
        oc.w = aC[a][i][3] + bCv.w;
        *reinterpret_cast<float4*>(&Bu[(size_t)gr * DN + gc]) = obu;
        *reinterpret_cast<float4*>(&Cc[(size_t)gr * DN + gc]) = oc;
      }
}

// ---------------------------------------------------------------------------
// Parallel scan over time. h[t] = a*h[t-1] + Bu[t] with a = exp(-exp(A_log[n]))
// constant per channel -> chunked scan with exact carry propagation.
// Pass 1: per-chunk local end-state (h0 = 0).
// ---------------------------------------------------------------------------
__global__ void k_scan1(const float* __restrict__ Bu, const float* __restrict__ Alog,
                        float* __restrict__ Hl) {
    const int n = threadIdx.x;   // 64 channels
    const int c = blockIdx.x;    // chunk
    const int b = blockIdx.y;    // batch
    const float a = expf(-expf(Alog[n]));
    const float* p = Bu + ((size_t)(b * SEQL + c * LCH)) * DN + n;
    float h = 0.f;
#pragma unroll
    for (int t = 0; t < LCH; t++) h = fmaf(a, h, p[(size_t)t * DN]);
    Hl[(b * DN + n) * CH + c] = h;
}

// Pass 2 (tiny, sequential over CH chunks): carry-in for each chunk.
__global__ void k_carry(const float* __restrict__ Hl, const float* __restrict__ Alog,
                        float* __restrict__ Hin) {
    const int i = threadIdx.x;        // b*64 + n, 512 threads
    const int n = i & 63;
    const float a  = expf(-expf(Alog[n]));
    const float aL = powf(a, (float)LCH);
    float hend = 0.f;
    for (int c = 0; c < CH; c++) {
        Hin[(size_t)i * CH + c] = hend;           // h before chunk c
        hend = fmaf(aL, hend, Hl[(size_t)i * CH + c]);
    }
}

// Pass 3: re-run local scan seeded with carry, emit ys = C*h.
__global__ void k_scan2(const float* __restrict__ Bu, const float* __restrict__ Cc,
                        const float* __restrict__ Hin, const float* __restrict__ Alog,
                        float* __restrict__ Ys) {
    const int n = threadIdx.x;
    const int c = blockIdx.x;
    const int b = blockIdx.y;
    const float a = expf(-expf(Alog[n]));
    float h = Hin[((size_t)(b * DN + n)) * CH + c];
    const size_t base = ((size_t)(b * SEQL + c * LCH)) * DN + n;
#pragma unroll
    for (int t = 0; t < LCH; t++) {
        h = fmaf(a, h, Bu[base + (size_t)t * DN]);
        Ys[base + (size_t)t * DN] = Cc[base + (size_t)t * DN] * h;
    }
}

// ---------------------------------------------------------------------------
// GEMM3: T = Ys @ W_s2o + D*U, written IN PLACE over U (same element positions
// read in the epilogue only -> race-free).  K = 64.
// ---------------------------------------------------------------------------
__global__ __launch_bounds__(256) void k_gemm_s2o(
    const float* __restrict__ Ys, const float* __restrict__ W,
    const float* __restrict__ Dv, float* __restrict__ U)
{
    constexpr int BM = 128, BN = 128, BK = 32;
    __shared__ float As[BK][BM + 4];
    __shared__ float Bs[BK][BN + 4];
    const int tid = threadIdx.x;
    const int m0 = blockIdx.y * BM;
    const int n0 = blockIdx.x * BN;
    const int tx = tid & 15, ty = tid >> 4;

    float acc[2][2][4][4];
#pragma unroll
    for (int a = 0; a < 2; a++)
#pragma unroll
      for (int b = 0; b < 2; b++)
#pragma unroll
        for (int i = 0; i < 4; i++)
#pragma unroll
          for (int j = 0; j < 4; j++) acc[a][b][i][j] = 0.f;

    for (int k0 = 0; k0 < DN; k0 += BK) {
#pragma unroll
        for (int j = 0; j < 4; j++) {
            int id = tid + j * 256;
            int r = id >> 3, c4 = id & 7;
            float4 v = *reinterpret_cast<const float4*>(&Ys[(size_t)(m0 + r) * DN + k0 + c4 * 4]);
            As[c4 * 4 + 0][r] = v.x;
            As[c4 * 4 + 1][r] = v.y;
            As[c4 * 4 + 2][r] = v.z;
            As[c4 * 4 + 3][r] = v.w;
        }
#pragma unroll
        for (int j = 0; j < 4; j++) {
            int id = tid + j * 256;
            int r = id >> 5, c4 = id & 31;
            float4 v = *reinterpret_cast<const float4*>(&W[(size_t)(k0 + r) * DM + n0 + c4 * 4]);
            *reinterpret_cast<float4*>(&Bs[r][c4 * 4]) = v;
        }
        __syncthreads();
#pragma unroll
        for (int k = 0; k < BK; k++) {
            float4 a0 = *reinterpret_cast<const float4*>(&As[k][ty * 4]);
            float4 a1 = *reinterpret_cast<const float4*>(&As[k][64 + ty * 4]);
            float4 b0 = *reinterpret_cast<const float4*>(&Bs[k][tx * 4]);
            float4 b1 = *reinterpret_cast<const float4*>(&Bs[k][64 + tx * 4]);
            float av[2][4] = {{a0.x, a0.y, a0.z, a0.w}, {a1.x, a1.y, a1.z, a1.w}};
            float bv[2][4] = {{b0.x, b0.y, b0.z, b0.w}, {b1.x, b1.y, b1.z, b1.w}};
#pragma unroll
            for (int a = 0; a < 2; a++)
#pragma unroll
              for (int b = 0; b < 2; b++)
#pragma unroll
                for (int i = 0; i < 4; i++)
#pragma unroll
                  for (int j = 0; j < 4; j++)
                    acc[a][b][i][j] = fmaf(av[a][i], bv[b][j], acc[a][b][i][j]);
        }
        __syncthreads();
    }
#pragma unroll
    for (int a = 0; a < 2; a++)
#pragma unroll
      for (int i = 0; i < 4; i++) {
        int gr = m0 + a * 64 + ty * 4 + i;
#pragma unroll
        for (int b = 0; b < 2; b++) {
          int gc = n0 + b * 64 + tx * 4;
          float4 u  = *reinterpret_cast<const float4*>(&U[(size_t)gr * DM + gc]);
          float4 dv = *reinterpret_cast<const float4*>(&Dv[gc]);
          float4 o;
          o.x = acc[a][b][i][0] + dv.x * u.x;
          o.y = acc[a][b][i][1] + dv.y * u.y;
          o.z = acc[a][b][i][2] + dv.z * u.z;
          o.w = acc[a][b][i][3] + dv.w * u.w;
          *reinterpret_cast<float4*>(&U[(size_t)gr * DM + gc]) = o;
        }
      }
}

// ---------------------------------------------------------------------------
// GEMM4: out = T @ W_out + b_out + X (residual)
// ---------------------------------------------------------------------------
__global__ __launch_bounds__(256) void k_gemm_out(
    const float* __restrict__ T, const float* __restrict__ W,
    const float* __restrict__ bvec, const float* __restrict__ X,
    float* __restrict__ Out)
{
    constexpr int BM = 128, BN = 128, BK = 32;
    __shared__ float As[BK][BM + 4];
    __shared__ float Bs[BK][BN + 4];
    const int tid = threadIdx.x;
    const int m0 = blockIdx.y * BM;
    const int n0 = blockIdx.x * BN;
    const int tx = tid & 15, ty = tid >> 4;

    float acc[2][2][4][4];
#pragma unroll
    for (int a = 0; a < 2; a++)
#pragma unroll
      for (int b = 0; b < 2; b++)
#pragma unroll
        for (int i = 0; i < 4; i++)
#pragma unroll
          for (int j = 0; j < 4; j++) acc[a][b][i][j] = 0.f;

    for (int k0 = 0; k0 < DM; k0 += BK) {
#pragma unroll
        for (int j = 0; j < 4; j++) {
            int id = tid + j * 256;
            int r = id >> 3, c4 = id & 7;
            float4 v = *reinterpret_cast<const float4*>(&T[(size_t)(m0 + r) * DM + k0 + c4 * 4]);
            As[c4 * 4 + 0][r] = v.x;
            As[c4 * 4 + 1][r] = v.y;
            As[c4 * 4 + 2][r] = v.z;
            As[c4 * 4 + 3][r] = v.w;
        }
#pragma unroll
        for (int j = 0; j < 4; j++) {
            int id = tid + j * 256;
            int r = id >> 5, c4 = id & 31;
            float4 v = *reinterpret_cast<const float4*>(&W[(size_t)(k0 + r) * DM + n0 + c4 * 4]);
            *reinterpret_cast<float4*>(&Bs[r][c4 * 4]) = v;
        }
        __syncthreads();
#pragma unroll
        for (int k = 0; k < BK; k++) {
            float4 a0 = *reinterpret_cast<const float4*>(&As[k][ty * 4]);
            float4 a1 = *reinterpret_cast<const float4*>(&As[k][64 + ty * 4]);
            float4 b0 = *reinterpret_cast<const float4*>(&Bs[k][tx * 4]);
            float4 b1 = *reinterpret_cast<const float4*>(&Bs[k][64 + tx * 4]);
            float av[2][4] = {{a0.x, a0.y, a0.z, a0.w}, {a1.x, a1.y, a1.z, a1.w}};
            float bv[2][4] = {{b0.x, b0.y, b0.z, b0.w}, {b1.x, b1.y, b1.z, b1.w}};
#pragma unroll
            for (int a = 0; a < 2; a++)
#pragma unroll
              for (int b = 0; b < 2; b++)
#pragma unroll
                for (int i = 0; i < 4; i++)
#pragma unroll
                  for (int j = 0; j < 4; j++)
                    acc[a][b][i][j] = fmaf(av[a][i], bv[b][j], acc[a][b][i][j]);
        }
        __syncthreads();
    }
#pragma unroll
    for (int a = 0; a < 2; a++)
#pragma unroll
      for (int i = 0; i < 4; i++) {
        int gr = m0 + a * 64 + ty * 4 + i;
#pragma unroll
        for (int b = 0; b < 2; b++) {
          int gc = n0 + b * 64 + tx * 4;
          float4 bias = *reinterpret_cast<const float4*>(&bvec[gc]);
          float4 res  = *reinterpret_cast<const float4*>(&X[(size_t)gr * DM + gc]);
          float4 o;
          o.x = acc[a][b][i][0] + bias.x + res.x;
          o.y = acc[a][b][i][1] + bias.y + res.y;
          o.z = acc[a][b][i][2] + bias.z + res.z;
          o.w = acc[a][b][i][3] + bias.w + res.w;
          *reinterpret_cast<float4*>(&Out[(size_t)gr * DM + gc]) = o;
        }
      }
}

// ---------------------------------------------------------------------------
extern "C" void kernel_launch(void* const* d_in, const int* in_sizes, int n_in,
                              void* d_out, int out_size, void* d_ws, size_t ws_size,
                              hipStream_t stream) {
    const float* X     = (const float*)d_in[0];
    const float* gamma = (const float*)d_in[1];
    const float* beta  = (const float*)d_in[2];
    const float* W_in  = (const float*)d_in[3];
    const float* b_in  = (const float*)d_in[4];
    const float* W_xs  = (const float*)d_in[5];
    const float* W_B   = (const float*)d_in[6];
    const float* b_B   = (const float*)d_in[7];
    const float* W_C   = (const float*)d_in[8];
    const float* b_C   = (const float*)d_in[9];
    const float* A_log = (const float*)d_in[10];
    const float* Dv    = (const float*)d_in[11];
    const float* W_s2o = (const float*)d_in[12];
    const float* W_out = (const float*)d_in[13];
    const float* b_out = (const float*)d_in[14];
    float* out = (float*)d_out;

    const int M = in_sizes[0] / DM;     // 32768 rows (B*S)
    const int B = M / SEQL;             // 8

    // Workspace layout (floats), ~93 MB total.
    float* ws    = (float*)d_ws;
    float* U     = ws;                              // M*DM   (reused in place as T)
    float* Bu    = U  + (size_t)M * DM;             // M*DN
    float* Cc    = Bu + (size_t)M * DN;             // M*DN
    float* Ys    = Cc + (size_t)M * DN;             // M*DN
    float* stats = Ys + (size_t)M * DN;             // 2*M
    float* Hl    = stats + (size_t)2 * M;           // B*DN*CH
    float* Hin   = Hl + (size_t)B * DN * CH;        // B*DN*CH

    k_lnstats<<<M / 4, 256, 0, stream>>>(X, stats);
    k_gemm_in<<<dim3(DM / 128, M / 128), 256, 0, stream>>>(X, stats, gamma, beta, W_in, b_in, U);
    k_gemm_bcx<<<dim3(M / 128), 256, 0, stream>>>(U, W_xs, W_B, b_B, W_C, b_C, Bu, Cc);
    k_scan1<<<dim3(CH, B), 64, 0, stream>>>(Bu, A_log, Hl);
    k_carry<<<1, B * DN, 0, stream>>>(Hl, A_log, Hin);
    k_scan2<<<dim3(CH, B), 64, 0, stream>>>(Bu, Cc, Hin, A_log, Ys);
    k_gemm_s2o<<<dim3(DM / 128, M / 128), 256, 0, stream>>>(Ys, W_s2o, Dv, U);
    k_gemm_out<<<dim3(DM / 128, M / 128), 256, 0, stream>>>(U, W_out, b_out, X, out);
}

// Round 2
// 265.037 us; speedup vs baseline: 2.2119x; 2.2119x over previous
//
#include <hip/hip_runtime.h>
#include <cstddef>

typedef unsigned short u16;

// Problem constants
constexpr int DM   = 512;    // d_model
constexpr int DN   = 64;     // d_state
constexpr int SEQL = 4096;
constexpr int CH   = 128;            // chunks per sequence for parallel scan
constexpr int LCH  = SEQL / CH;      // 32 steps per chunk

typedef __attribute__((ext_vector_type(8))) short bf16x8;
typedef __attribute__((ext_vector_type(4))) float f32x4;

__device__ inline u16 f2bf(float f) {
    unsigned int u = __float_as_uint(f);
    unsigned int r = u + 0x7FFFu + ((u >> 16) & 1u);   // round-to-nearest-even
    return (u16)(r >> 16);
}

__device__ inline void gload_lds16(const void* g, void* l) {
    __builtin_amdgcn_global_load_lds(
        (const __attribute__((address_space(1))) void*)g,
        (__attribute__((address_space(3))) void*)l, 16, 0, 0);
}

// ---------------------------------------------------------------------------
// LayerNorm -> bf16: one wave per row of 512, writes Xn bf16.
// ---------------------------------------------------------------------------
__global__ __launch_bounds__(256) void k_ln(const float* __restrict__ X,
                                            const float* __restrict__ gamma,
                                            const float* __restrict__ beta,
                                            u16* __restrict__ Xn) {
    const int lane = threadIdx.x & 63;
    const int w    = threadIdx.x >> 6;
    const size_t row = (size_t)blockIdx.x * 4 + w;
    const float* xr = X + row * DM;
    float4 v0 = *reinterpret_cast<const float4*>(&xr[lane * 8]);
    float4 v1 = *reinterpret_cast<const float4*>(&xr[lane * 8 + 4]);
    float s  = v0.x + v0.y + v0.z + v0.w + v1.x + v1.y + v1.z + v1.w;
    float s2 = v0.x*v0.x + v0.y*v0.y + v0.z*v0.z + v0.w*v0.w
             + v1.x*v1.x + v1.y*v1.y + v1.z*v1.z + v1.w*v1.w;
#pragma unroll
    for (int o = 32; o > 0; o >>= 1) {
        s  += __shfl_xor(s, o);
        s2 += __shfl_xor(s2, o);
    }
    const float mu = s * (1.0f / DM);
    const float rs = rsqrtf(s2 * (1.0f / DM) - mu * mu + 1e-3f);
    float4 g0 = *reinterpret_cast<const float4*>(&gamma[lane * 8]);
    float4 g1 = *reinterpret_cast<const float4*>(&gamma[lane * 8 + 4]);
    float4 b0 = *reinterpret_cast<const float4*>(&beta[lane * 8]);
    float4 b1 = *reinterpret_cast<const float4*>(&beta[lane * 8 + 4]);
    union { u16 h[8]; uint4 v; } pk;
    pk.h[0] = f2bf((v0.x - mu) * rs * g0.x + b0.x);
    pk.h[1] = f2bf((v0.y - mu) * rs * g0.y + b0.y);
    pk.h[2] = f2bf((v0.z - mu) * rs * g0.z + b0.z);
    pk.h[3] = f2bf((v0.w - mu) * rs * g0.w + b0.w);
    pk.h[4] = f2bf((v1.x - mu) * rs * g1.x + b1.x);
    pk.h[5] = f2bf((v1.y - mu) * rs * g1.y + b1.y);
    pk.h[6] = f2bf((v1.z - mu) * rs * g1.z + b1.z);
    pk.h[7] = f2bf((v1.w - mu) * rs * g1.w + b1.w);
    *reinterpret_cast<uint4*>(&Xn[row * DM + lane * 8]) = pk.v;
}

// ---------------------------------------------------------------------------
// Weight transpose+convert: Wt[n][k] = bf16(W[k][n]) for 512x512.
// ---------------------------------------------------------------------------
__global__ __launch_bounds__(256) void k_wtrans(const float* __restrict__ W,
                                                u16* __restrict__ Wt) {
    __shared__ float tile[64][65];
    const int bx = blockIdx.x, by = blockIdx.y;   // bx: n-tile, by: k-tile
    const int tx = threadIdx.x & 63, ty = threadIdx.x >> 6;
#pragma unroll
    for (int r = ty; r < 64; r += 4)
        tile[r][tx] = W[(size_t)(by * 64 + r) * DM + bx * 64 + tx];
    __syncthreads();
#pragma unroll
    for (int r = ty; r < 64; r += 4)
        Wt[(size_t)(bx * 64 + r) * DM + by * 64 + tx] = f2bf(tile[tx][r]);
}

// ---------------------------------------------------------------------------
// bf16 MFMA GEMM: Out[M,512] = A[M,512] @ Bt^T + bias (+ resid).
// A bf16 row-major [M][512]; Bt bf16 [N=512][K=512] (pre-transposed weight).
// 128x128 tile, BK=32, 4 waves (2x2), 16x16x32 MFMA, global_load_lds staging.
// ---------------------------------------------------------------------------
template <bool RES>
__global__ __launch_bounds__(256) void k_mfma512(
    const u16* __restrict__ A, const u16* __restrict__ Bt,
    const float* __restrict__ bias, const float* __restrict__ resid,
    float* __restrict__ Out)
{
    constexpr int BK = 32;
    __shared__ u16 As[128 * BK];   // [row][k] linear, 8 KB
    __shared__ u16 Bs[128 * BK];   // [col][k] linear, 8 KB
    const int tid  = threadIdx.x;
    const int lane = tid & 63;
    const int w    = tid >> 6;
    const int wr   = w >> 1, wc = w & 1;     // wave 2x2 -> 64x64 each
    const int m0   = blockIdx.y * 128;
    const int n0   = blockIdx.x * 128;

    f32x4 acc[4][4];
#pragma unroll
    for (int i = 0; i < 4; i++)
#pragma unroll
      for (int j = 0; j < 4; j++) acc[i][j] = (f32x4){0.f, 0.f, 0.f, 0.f};

    // staging: thread t covers (row=t>>2, k-octet=t&3); two halves of 64 rows
    const int srow = tid >> 2;
    const int sk   = (tid & 3) * 8;
    const u16* aptr0 = A  + (size_t)(m0 + srow) * DM + sk;
    const u16* aptr1 = aptr0 + (size_t)64 * DM;
    const u16* bptr0 = Bt + (size_t)(n0 + srow) * DM + sk;
    const u16* bptr1 = bptr0 + (size_t)64 * DM;
    u16* asB0 = As + w * 512;          // wave-uniform LDS bases (bytes: w*1024)
    u16* asB1 = As + 2048 + w * 512;
    u16* bsB0 = Bs + w * 512;
    u16* bsB1 = Bs + 2048 + w * 512;

    // fragment read offsets (ushort units)
    const int kg = lane >> 4;          // k-octet group 0..3
    const int lr = lane & 15;
    const int aoff = (wr * 64 + lr) * BK + kg * 8;
    const int boff = (wc * 64 + lr) * BK + kg * 8;

    for (int k0 = 0; k0 < DM; k0 += BK) {
        gload_lds16(aptr0, asB0);
        gload_lds16(aptr1, asB1);
        gload_lds16(bptr0, bsB0);
        gload_lds16(bptr1, bsB1);
        aptr0 += BK; aptr1 += BK; bptr0 += BK; bptr1 += BK;
        __syncthreads();               // vmcnt(0) drained before barrier
        bf16x8 af[4], bfr[4];
#pragma unroll
        for (int i = 0; i < 4; i++)
            af[i]  = *reinterpret_cast<const bf16x8*>(&As[aoff + i * 16 * BK]);
#pragma unroll
        for (int j = 0; j < 4; j++)
            bfr[j] = *reinterpret_cast<const bf16x8*>(&Bs[boff + j * 16 * BK]);
#pragma unroll
        for (int i = 0; i < 4; i++)
#pragma unroll
          for (int j = 0; j < 4; j++)
            acc[i][j] = __builtin_amdgcn_mfma_f32_16x16x32_bf16(af[i], bfr[j], acc[i][j], 0, 0, 0);
        __syncthreads();
    }

    // epilogue: C/D layout col=lane&15, row=(lane>>4)*4+reg
#pragma unroll
    for (int j = 0; j < 4; j++) {
        const int col = n0 + wc * 64 + j * 16 + lr;
        const float bv = bias[col];
#pragma unroll
        for (int i = 0; i < 4; i++) {
            const int rbase = m0 + wr * 64 + i * 16 + kg * 4;
#pragma unroll
            for (int r = 0; r < 4; r++) {
                float v = acc[i][j][r] + bv;
                const size_t idx = (size_t)(rbase + r) * DM + col;
                if (RES) v += resid[idx];
                Out[idx] = v;
            }
        }
    }
}

// ---------------------------------------------------------------------------
// GEMM2 (fp32): xs = U@W_xs, Bm = U@W_B + b_B, Cm = U@W_C + b_C.
// Writes Bu = Bm*xs and Cc = Cm.
// ---------------------------------------------------------------------------
__global__ __launch_bounds__(256) void k_gemm_bcx(
    const float* __restrict__ U,
    const float* __restrict__ Wxs, const float* __restrict__ Wb,
    const float* __restrict__ bB, const float* __restrict__ Wc,
    const float* __restrict__ bC,
    float* __restrict__ Bu, float* __restrict__ Cc)
{
    constexpr int BM = 128, BK = 32;
    __shared__ float As[BK][BM + 4];
    __shared__ float Bs[3][BK][DN + 4];
    const int tid = threadIdx.x;
    const int m0 = blockIdx.x * BM;
    const int tx = tid & 15, ty = tid >> 4;

    float aX[2][4][4], aB[2][4][4], aC[2][4][4];
#pragma unroll
    for (int a = 0; a < 2; a++)
#pragma unroll
      for (int i = 0; i < 4; i++)
#pragma unroll
        for (int j = 0; j < 4; j++) { aX[a][i][j] = 0.f; aB[a][i][j] = 0.f; aC[a][i][j] = 0.f; }

    for (int k0 = 0; k0 < DM; k0 += BK) {
#pragma unroll
        for (int j = 0; j < 4; j++) {
            int id = tid + j * 256;
            int r = id >> 3, c4 = id & 7;
            float4 v = *reinterpret_cast<const float4*>(&U[(size_t)(m0 + r) * DM + k0 + c4 * 4]);
            As[c4 * 4 + 0][r] = v.x;
            As[c4 * 4 + 1][r] = v.y;
            As[c4 * 4 + 2][r] = v.z;
            As[c4 * 4 + 3][r] = v.w;
        }
#pragma unroll
        for (int j = 0; j < 2; j++) {
            int id = tid + j * 256;
            int r = id >> 4, c4 = id & 15;
            *reinterpret_cast<float4*>(&Bs[0][r][c4 * 4]) =
                *reinterpret_cast<const float4*>(&Wxs[(size_t)(k0 + r) * DN + c4 * 4]);
            *reinterpret_cast<float4*>(&Bs[1][r][c4 * 4]) =
                *reinterpret_cast<const float4*>(&Wb[(size_t)(k0 + r) * DN + c4 * 4]);
            *reinterpret_cast<float4*>(&Bs[2][r][c4 * 4]) =
                *reinterpret_cast<const float4*>(&Wc[(size_t)(k0 + r) * DN + c4 * 4]);
        }
        __syncthreads();
#pragma unroll
        for (int k = 0; k < BK; k++) {
            float4 a0 = *reinterpret_cast<const float4*>(&As[k][ty * 4]);
            float4 a1 = *reinterpret_cast<const float4*>(&As[k][64 + ty * 4]);
            float4 bx = *reinterpret_cast<const float4*>(&Bs[0][k][tx * 4]);
            float4 bb = *reinterpret_cast<const float4*>(&Bs[1][k][tx * 4]);
            float4 bc = *reinterpret_cast<const float4*>(&Bs[2][k][tx * 4]);
            float av[2][4] = {{a0.x, a0.y, a0.z, a0.w}, {a1.x, a1.y, a1.z, a1.w}};
            float xv[4] = {bx.x, bx.y, bx.z, bx.w};
            float bv[4] = {bb.x, bb.y, bb.z, bb.w};
            float cv[4] = {bc.x, bc.y, bc.z, bc.w};
#pragma unroll
            for (int a = 0; a < 2; a++)
#pragma unroll
              for (int i = 0; i < 4; i++)
#pragma unroll
                for (int j = 0; j < 4; j++) {
                    aX[a][i][j] = fmaf(av[a][i], xv[j], aX[a][i][j]);
                    aB[a][i][j] = fmaf(av[a][i], bv[j], aB[a][i][j]);
                    aC[a][i][j] = fmaf(av[a][i], cv[j], aC[a][i][j]);
                }
        }
        __syncthreads();
    }
#pragma unroll
    for (int a = 0; a < 2; a++)
#pragma unroll
      for (int i = 0; i < 4; i++) {
        int gr = m0 + a * 64 + ty * 4 + i;
        int gc = tx * 4;
        float4 bBv = *reinterpret_cast<const float4*>(&bB[gc]);
        float4 bCv = *reinterpret_cast<const float4*>(&bC[gc]);
        float4 obu, oc;
        obu.x = (aB[a][i][0] + bBv.x) * aX[a][i][0];
        obu.y = (aB[a][i][1] + bBv.y) * aX[a][i][1];
        obu.z = (aB[a][i][2] + bBv.z) * aX[a][i][2];
        obu.w = (aB[a][i][3] + bBv.w) * aX[a][i][3];
        oc.x = aC[a][i][0] + bCv.x;
        oc.y = aC[a][i][1] + bCv.y;
        oc.z = aC[a][i][2] + bCv.z;
        oc.w = aC[a][i][3] + bCv.w;
        *reinterpret_cast<float4*>(&Bu[(size_t)gr * DN + gc]) = obu;
        *reinterpret_cast<float4*>(&Cc[(size_t)gr * DN + gc]) = oc;
      }
}

// ---------------------------------------------------------------------------
// Chunked parallel scan (exact): h[t] = a*h[t-1] + Bu[t], a const per channel.
// ---------------------------------------------------------------------------
__global__ void k_scan1(const float* __restrict__ Bu, const float* __restrict__ Alog,
                        float* __restrict__ Hl) {
    const int n = threadIdx.x;
    const int c = blockIdx.x;
    const int b = blockIdx.y;
    const float a = expf(-expf(Alog[n]));
    const float* p = Bu + ((size_t)(b * SEQL + c * LCH)) * DN + n;
    float h = 0.f;
#pragma unroll
    for (int t = 0; t < LCH; t++) h = fmaf(a, h, p[(size_t)t * DN]);
    Hl[(b * DN + n) * CH + c] = h;
}

__global__ void k_carry(const float* __restrict__ Hl, const float* __restrict__ Alog,
                        float* __restrict__ Hin) {
    const int i = threadIdx.x;        // b*64 + n
    const int n = i & 63;
    const float a  = expf(-expf(Alog[n]));
    const float aL = powf(a, (float)LCH);
    float hend = 0.f;
    for (int c = 0; c < CH; c++) {
        Hin[(size_t)i * CH + c] = hend;
        hend = fmaf(aL, hend, Hl[(size_t)i * CH + c]);
    }
}

__global__ void k_scan2(const float* __restrict__ Bu, const float* __restrict__ Cc,
                        const float* __restrict__ Hin, const float* __restrict__ Alog,
                        float* __restrict__ Ys) {
    const int n = threadIdx.x;
    const int c = blockIdx.x;
    const int b = blockIdx.y;
    const float a = expf(-expf(Alog[n]));
    float h = Hin[((size_t)(b * DN + n)) * CH + c];
    const size_t base = ((size_t)(b * SEQL + c * LCH)) * DN + n;
#pragma unroll
    for (int t = 0; t < LCH; t++) {
        h = fmaf(a, h, Bu[base + (size_t)t * DN]);
        Ys[base + (size_t)t * DN] = Cc[base + (size_t)t * DN] * h;
    }
}

// ---------------------------------------------------------------------------
// GEMM3 (fp32, K=64): T = Ys @ W_s2o + D*U  -> written as bf16 to Tb.
// ---------------------------------------------------------------------------
__global__ __launch_bounds__(256) void k_gemm_s2o(
    const float* __restrict__ Ys, const float* __restrict__ W,
    const float* __restrict__ Dv, const float* __restrict__ U,
    u16* __restrict__ Tb)
{
    constexpr int BM = 128, BN = 128, BK = 32;
    __shared__ float As[BK][BM + 4];
    __shared__ float Bs[BK][BN + 4];
    const int tid = threadIdx.x;
    const int m0 = blockIdx.y * BM;
    const int n0 = blockIdx.x * BN;
    const int tx = tid & 15, ty = tid >> 4;

    float acc[2][2][4][4];
#pragma unroll
    for (int a = 0; a < 2; a++)
#pragma unroll
      for (int b = 0; b < 2; b++)
#pragma unroll
        for (int i = 0; i < 4; i++)
#pragma unroll
          for (int j = 0; j < 4; j++) acc[a][b][i][j] = 0.f;

    for (int k0 = 0; k0 < DN; k0 += BK) {
#pragma unroll
        for (int j = 0; j < 4; j++) {
            int id = tid + j * 256;
            int r = id >> 3, c4 = id & 7;
            float4 v = *reinterpret_cast<const float4*>(&Ys[(size_t)(m0 + r) * DN + k0 + c4 * 4]);
            As[c4 * 4 + 0][r] = v.x;
            As[c4 * 4 + 1][r] = v.y;
            As[c4 * 4 + 2][r] = v.z;
            As[c4 * 4 + 3][r] = v.w;
        }
#pragma unroll
        for (int j = 0; j < 4; j++) {
            int id = tid + j * 256;
            int r = id >> 5, c4 = id & 31;
            float4 v = *reinterpret_cast<const float4*>(&W[(size_t)(k0 + r) * DM + n0 + c4 * 4]);
            *reinterpret_cast<float4*>(&Bs[r][c4 * 4]) = v;
        }
        __syncthreads();
#pragma unroll
        for (int k = 0; k < BK; k++) {
            float4 a0 = *reinterpret_cast<const float4*>(&As[k][ty * 4]);
            float4 a1 = *reinterpret_cast<const float4*>(&As[k][64 + ty * 4]);
            float4 b0 = *reinterpret_cast<const float4*>(&Bs[k][tx * 4]);
            float4 b1 = *reinterpret_cast<const float4*>(&Bs[k][64 + tx * 4]);
            float av[2][4] = {{a0.x, a0.y, a0.z, a0.w}, {a1.x, a1.y, a1.z, a1.w}};
            float bv[2][4] = {{b0.x, b0.y, b0.z, b0.w}, {b1.x, b1.y, b1.z, b1.w}};
#pragma unroll
            for (int a = 0; a < 2; a++)
#pragma unroll
              for (int b = 0; b < 2; b++)
#pragma unroll
                for (int i = 0; i < 4; i++)
#pragma unroll
                  for (int j = 0; j < 4; j++)
                    acc[a][b][i][j] = fmaf(av[a][i], bv[b][j], acc[a][b][i][j]);
        }
        __syncthreads();
    }
#pragma unroll
    for (int a = 0; a < 2; a++)
#pragma unroll
      for (int i = 0; i < 4; i++) {
        int gr = m0 + a * 64 + ty * 4 + i;
#pragma unroll
        for (int b = 0; b < 2; b++) {
          int gc = n0 + b * 64 + tx * 4;
          float4 u  = *reinterpret_cast<const float4*>(&U[(size_t)gr * DM + gc]);
          float4 dv = *reinterpret_cast<const float4*>(&Dv[gc]);
          union { u16 h[4]; uint2 v; } pk;
          pk.h[0] = f2bf(acc[a][b][i][0] + dv.x * u.x);
          pk.h[1] = f2bf(acc[a][b][i][1] + dv.y * u.y);
          pk.h[2] = f2bf(acc[a][b][i][2] + dv.z * u.z);
          pk.h[3] = f2bf(acc[a][b][i][3] + dv.w * u.w);
          *reinterpret_cast<uint2*>(&Tb[(size_t)gr * DM + gc]) = pk.v;
        }
      }
}

// ---------------------------------------------------------------------------
extern "C" void kernel_launch(void* const* d_in, const int* in_sizes, int n_in,
                              void* d_out, int out_size, void* d_ws, size_t ws_size,
                              hipStream_t stream) {
    const float* X     = (const float*)d_in[0];
    const float* gamma = (const float*)d_in[1];
    const float* beta  = (const float*)d_in[2];
    const float* W_in  = (const float*)d_in[3];
    const float* b_in  = (const float*)d_in[4];
    const float* W_xs  = (const float*)d_in[5];
    const float* W_B   = (const float*)d_in[6];
    const float* b_B   = (const float*)d_in[7];
    const float* W_C   = (const float*)d_in[8];
    const float* b_C   = (const float*)d_in[9];
    const float* A_log = (const float*)d_in[10];
    const float* Dv    = (const float*)d_in[11];
    const float* W_s2o = (const float*)d_in[12];
    const float* W_out = (const float*)d_in[13];
    const float* b_out = (const float*)d_in[14];
    float* out = (float*)d_out;

    const int M = in_sizes[0] / DM;     // 32768 rows (B*S)
    const int B = M / SEQL;             // 8

    // Workspace layout (~121.5 MB)
    float* ws  = (float*)d_ws;
    float* U   = ws;                               // M*DM fp32
    float* Bu  = U  + (size_t)M * DM;              // M*DN
    float* Cc  = Bu + (size_t)M * DN;              // M*DN
    float* Ys  = Cc + (size_t)M * DN;              // M*DN
    float* Hl  = Ys + (size_t)M * DN;              // B*DN*CH
    float* Hin = Hl + (size_t)B * DN * CH;         // B*DN*CH
    u16* Xn    = (u16*)(Hin + (size_t)B * DN * CH); // M*DM bf16
    u16* Tb    = Xn;                                // alias: Xn dead before GEMM3
    u16* WinT  = Xn + (size_t)M * DM;               // 512*512 bf16
    u16* WoutT = WinT + (size_t)DM * DM;            // 512*512 bf16

    k_ln<<<M / 4, 256, 0, stream>>>(X, gamma, beta, Xn);
    k_wtrans<<<dim3(8, 8), 256, 0, stream>>>(W_in, WinT);
    k_wtrans<<<dim3(8, 8), 256, 0, stream>>>(W_out, WoutT);
    k_mfma512<false><<<dim3(DM / 128, M / 128), 256, 0, stream>>>(Xn, WinT, b_in, nullptr, U);
    k_gemm_bcx<<<dim3(M / 128), 256, 0, stream>>>(U, W_xs, W_B, b_B, W_C, b_C, Bu, Cc);
    k_scan1<<<dim3(CH, B), 64, 0, stream>>>(Bu, A_log, Hl);
    k_carry<<<1, B * DN, 0, stream>>>(Hl, A_log, Hin);
    k_scan2<<<dim3(CH, B), 64, 0, stream>>>(Bu, Cc, Hin, A_log, Ys);
    k_gemm_s2o<<<dim3(DM / 128, M / 128), 256, 0, stream>>>(Ys, W_s2o, Dv, U, Tb);
    k_mfma512<true><<<dim3(DM / 128, M / 128), 256, 0, stream>>>(Tb, WoutT, b_out, X, out);
}

// Round 3
// 186.041 us; speedup vs baseline: 3.1511x; 1.4246x over previous
//
#include <hip/hip_runtime.h>
#include <cstddef>

typedef unsigned short u16;

// Problem constants
constexpr int DM   = 512;    // d_model
constexpr int DN   = 64;     // d_state
constexpr int SEQL = 4096;
constexpr int CH   = 128;            // chunks per sequence for parallel scan
constexpr int LCH  = SEQL / CH;      // 32 steps per chunk

typedef __attribute__((ext_vector_type(8))) short bf16x8;
typedef __attribute__((ext_vector_type(4))) float f32x4;

__device__ inline u16 f2bf(float f) {
    unsigned int u = __float_as_uint(f);
    unsigned int r = u + 0x7FFFu + ((u >> 16) & 1u);   // round-to-nearest-even
    return (u16)(r >> 16);
}
__device__ inline float bf2f(u16 h) {
    return __uint_as_float(((unsigned int)h) << 16);
}

__device__ inline void gload_lds16(const void* g, void* l) {
    __builtin_amdgcn_global_load_lds(
        (const __attribute__((address_space(1))) void*)g,
        (__attribute__((address_space(3))) void*)l, 16, 0, 0);
}

// ---------------------------------------------------------------------------
// LayerNorm -> bf16: one wave per row of 512, writes Xn bf16.
// ---------------------------------------------------------------------------
__global__ __launch_bounds__(256) void k_ln(const float* __restrict__ X,
                                            const float* __restrict__ gamma,
                                            const float* __restrict__ beta,
                                            u16* __restrict__ Xn) {
    const int lane = threadIdx.x & 63;
    const int w    = threadIdx.x >> 6;
    const size_t row = (size_t)blockIdx.x * 4 + w;
    const float* xr = X + row * DM;
    float4 v0 = *reinterpret_cast<const float4*>(&xr[lane * 8]);
    float4 v1 = *reinterpret_cast<const float4*>(&xr[lane * 8 + 4]);
    float s  = v0.x + v0.y + v0.z + v0.w + v1.x + v1.y + v1.z + v1.w;
    float s2 = v0.x*v0.x + v0.y*v0.y + v0.z*v0.z + v0.w*v0.w
             + v1.x*v1.x + v1.y*v1.y + v1.z*v1.z + v1.w*v1.w;
#pragma unroll
    for (int o = 32; o > 0; o >>= 1) {
        s  += __shfl_xor(s, o);
        s2 += __shfl_xor(s2, o);
    }
    const float mu = s * (1.0f / DM);
    const float rs = rsqrtf(s2 * (1.0f / DM) - mu * mu + 1e-3f);
    float4 g0 = *reinterpret_cast<const float4*>(&gamma[lane * 8]);
    float4 g1 = *reinterpret_cast<const float4*>(&gamma[lane * 8 + 4]);
    float4 b0 = *reinterpret_cast<const float4*>(&beta[lane * 8]);
    float4 b1 = *reinterpret_cast<const float4*>(&beta[lane * 8 + 4]);
    union { u16 h[8]; uint4 v; } pk;
    pk.h[0] = f2bf((v0.x - mu) * rs * g0.x + b0.x);
    pk.h[1] = f2bf((v0.y - mu) * rs * g0.y + b0.y);
    pk.h[2] = f2bf((v0.z - mu) * rs * g0.z + b0.z);
    pk.h[3] = f2bf((v0.w - mu) * rs * g0.w + b0.w);
    pk.h[4] = f2bf((v1.x - mu) * rs * g1.x + b1.x);
    pk.h[5] = f2bf((v1.y - mu) * rs * g1.y + b1.y);
    pk.h[6] = f2bf((v1.z - mu) * rs * g1.z + b1.z);
    pk.h[7] = f2bf((v1.w - mu) * rs * g1.w + b1.w);
    *reinterpret_cast<uint4*>(&Xn[row * DM + lane * 8]) = pk.v;
}

// ---------------------------------------------------------------------------
// Generalized transpose+convert: Wt[n*K + k] = bf16(W[k*N + n]), 64x64 tiles.
// grid (N/64, K/64)
// ---------------------------------------------------------------------------
__global__ __launch_bounds__(256) void k_wtransG(const float* __restrict__ W,
                                                 u16* __restrict__ Wt,
                                                 int K, int N) {
    __shared__ float tile[64][65];
    const int bx = blockIdx.x, by = blockIdx.y;
    const int tx = threadIdx.x & 63, ty = threadIdx.x >> 6;
#pragma unroll
    for (int r = ty; r < 64; r += 4)
        tile[r][tx] = W[(size_t)(by * 64 + r) * N + bx * 64 + tx];
    __syncthreads();
#pragma unroll
    for (int r = ty; r < 64; r += 4)
        Wt[(size_t)(bx * 64 + r) * K + by * 64 + tx] = f2bf(tile[tx][r]);
}

// ---------------------------------------------------------------------------
// bf16 MFMA GEMM (K=512): 128x128 tile, BK=32, 4 waves (2x2).
// MODE 0: Out = bf16(A@Bt^T + bias)            (GEMM1 -> Ub)
// MODE 1: Out = f32 (A@Bt^T + bias + resid)    (GEMM4 -> out)
// ---------------------------------------------------------------------------
template <int MODE>
__global__ __launch_bounds__(256) void k_mfma512(
    const u16* __restrict__ A, const u16* __restrict__ Bt,
    const float* __restrict__ bias, const float* __restrict__ resid,
    void* __restrict__ OutV)
{
    constexpr int BK = 32;
    __shared__ u16 As[128 * BK];   // 8 KB
    __shared__ u16 Bs[128 * BK];   // 8 KB
    const int tid  = threadIdx.x;
    const int lane = tid & 63;
    const int w    = tid >> 6;
    const int wr   = w >> 1, wc = w & 1;
    const int m0   = blockIdx.y * 128;
    const int n0   = blockIdx.x * 128;

    f32x4 acc[4][4];
#pragma unroll
    for (int i = 0; i < 4; i++)
#pragma unroll
      for (int j = 0; j < 4; j++) acc[i][j] = (f32x4){0.f, 0.f, 0.f, 0.f};

    const int srow = tid >> 2;
    const int sk   = (tid & 3) * 8;
    const u16* aptr0 = A  + (size_t)(m0 + srow) * DM + sk;
    const u16* aptr1 = aptr0 + (size_t)64 * DM;
    const u16* bptr0 = Bt + (size_t)(n0 + srow) * DM + sk;
    const u16* bptr1 = bptr0 + (size_t)64 * DM;
    u16* asB0 = As + w * 512;
    u16* asB1 = As + 2048 + w * 512;
    u16* bsB0 = Bs + w * 512;
    u16* bsB1 = Bs + 2048 + w * 512;

    const int kg = lane >> 4;
    const int lr = lane & 15;
    const int aoff = (wr * 64 + lr) * BK + kg * 8;
    const int boff = (wc * 64 + lr) * BK + kg * 8;

    for (int k0 = 0; k0 < DM; k0 += BK) {
        gload_lds16(aptr0, asB0);
        gload_lds16(aptr1, asB1);
        gload_lds16(bptr0, bsB0);
        gload_lds16(bptr1, bsB1);
        aptr0 += BK; aptr1 += BK; bptr0 += BK; bptr1 += BK;
        __syncthreads();
        bf16x8 af[4], bfr[4];
#pragma unroll
        for (int i = 0; i < 4; i++)
            af[i]  = *reinterpret_cast<const bf16x8*>(&As[aoff + i * 16 * BK]);
#pragma unroll
        for (int j = 0; j < 4; j++)
            bfr[j] = *reinterpret_cast<const bf16x8*>(&Bs[boff + j * 16 * BK]);
#pragma unroll
        for (int i = 0; i < 4; i++)
#pragma unroll
          for (int j = 0; j < 4; j++)
            acc[i][j] = __builtin_amdgcn_mfma_f32_16x16x32_bf16(af[i], bfr[j], acc[i][j], 0, 0, 0);
        __syncthreads();
    }

#pragma unroll
    for (int j = 0; j < 4; j++) {
        const int col = n0 + wc * 64 + j * 16 + lr;
        const float bv = bias[col];
#pragma unroll
        for (int i = 0; i < 4; i++) {
            const int rbase = m0 + wr * 64 + i * 16 + kg * 4;
#pragma unroll
            for (int r = 0; r < 4; r++) {
                const size_t idx = (size_t)(rbase + r) * DM + col;
                float v = acc[i][j][r] + bv;
                if (MODE == 0) {
                    ((u16*)OutV)[idx] = f2bf(v);
                } else {
                    ((float*)OutV)[idx] = v + resid[idx];
                }
            }
        }
    }
}

// ---------------------------------------------------------------------------
// GEMM2 (MFMA): [xs|Bm|Cm] = Ub @ WbcxT^T, WbcxT = [192][512] bf16.
// BM=64 tile -> 512 blocks. Wave w owns rows w*16..w*16+15, all 192 cols.
// Epilogue: Bu = (Bm+b_B)*xs, Cc = Cm+b_C  (thread-local pairing).
// ---------------------------------------------------------------------------
__global__ __launch_bounds__(256) void k_mfma_bcx(
    const u16* __restrict__ A, const u16* __restrict__ Bt,
    const float* __restrict__ bB, const float* __restrict__ bC,
    float* __restrict__ Bu, float* __restrict__ Cc)
{
    constexpr int BK = 32;
    __shared__ u16 As[64 * BK];    // 4 KB
    __shared__ u16 Bs[192 * BK];   // 12 KB
    const int tid  = threadIdx.x;
    const int lane = tid & 63;
    const int w    = tid >> 6;
    const int m0   = blockIdx.x * 64;

    f32x4 acc[12];
#pragma unroll
    for (int j = 0; j < 12; j++) acc[j] = (f32x4){0.f, 0.f, 0.f, 0.f};

    const int srow = tid >> 2;
    const int sk   = (tid & 3) * 8;
    const u16* aptr  = A  + (size_t)(m0 + srow) * DM + sk;
    const u16* bptr0 = Bt + (size_t)srow * DM + sk;
    const u16* bptr1 = bptr0 + (size_t)64 * DM;
    const u16* bptr2 = bptr0 + (size_t)128 * DM;
    u16* asB  = As + w * 512;
    u16* bsB0 = Bs + w * 512;
    u16* bsB1 = Bs + 2048 + w * 512;
    u16* bsB2 = Bs + 4096 + w * 512;

    const int kg = lane >> 4;
    const int lr = lane & 15;
    const int aoff = (w * 16 + lr) * BK + kg * 8;

    for (int k0 = 0; k0 < DM; k0 += BK) {
        gload_lds16(aptr,  asB);
        gload_lds16(bptr0, bsB0);
        gload_lds16(bptr1, bsB1);
        gload_lds16(bptr2, bsB2);
        aptr += BK; bptr0 += BK; bptr1 += BK; bptr2 += BK;
        __syncthreads();
        bf16x8 af = *reinterpret_cast<const bf16x8*>(&As[aoff]);
#pragma unroll
        for (int j = 0; j < 12; j++) {
            bf16x8 bfr = *reinterpret_cast<const bf16x8*>(&Bs[(j * 16 + lr) * BK + kg * 8]);
            acc[j] = __builtin_amdgcn_mfma_f32_16x16x32_bf16(af, bfr, acc[j], 0, 0, 0);
        }
        __syncthreads();
    }

#pragma unroll
    for (int j = 0; j < 4; j++) {
        const int col = j * 16 + lr;
        const float bBv = bB[col], bCv = bC[col];
#pragma unroll
        for (int r = 0; r < 4; r++) {
            const int grow = m0 + w * 16 + kg * 4 + r;
            const float xs = acc[j][r];
            const float bm = acc[j + 4][r] + bBv;
            const float cm = acc[j + 8][r] + bCv;
            Bu[(size_t)grow * DN + col] = bm * xs;
            Cc[(size_t)grow * DN + col] = cm;
        }
    }
}

// ---------------------------------------------------------------------------
// Chunked parallel scan (exact): h[t] = a*h[t-1] + Bu[t], a const per channel.
// ---------------------------------------------------------------------------
__global__ void k_scan1(const float* __restrict__ Bu, const float* __restrict__ Alog,
                        float* __restrict__ Hl) {
    const int n = threadIdx.x;
    const int c = blockIdx.x;
    const int b = blockIdx.y;
    const float a = expf(-expf(Alog[n]));
    const float* p = Bu + ((size_t)(b * SEQL + c * LCH)) * DN + n;
    float h = 0.f;
#pragma unroll
    for (int t = 0; t < LCH; t++) h = fmaf(a, h, p[(size_t)t * DN]);
    Hl[(b * DN + n) * CH + c] = h;
}

__global__ void k_carry(const float* __restrict__ Hl, const float* __restrict__ Alog,
                        float* __restrict__ Hin) {
    const int i = threadIdx.x;        // b*64 + n
    const int n = i & 63;
    const float a  = expf(-expf(Alog[n]));
    const float aL = powf(a, (float)LCH);
    float hend = 0.f;
    for (int c = 0; c < CH; c++) {
        Hin[(size_t)i * CH + c] = hend;
        hend = fmaf(aL, hend, Hl[(size_t)i * CH + c]);
    }
}

__global__ void k_scan2(const float* __restrict__ Bu, const float* __restrict__ Cc,
                        const float* __restrict__ Hin, const float* __restrict__ Alog,
                        u16* __restrict__ Ysb) {
    const int n = threadIdx.x;
    const int c = blockIdx.x;
    const int b = blockIdx.y;
    const float a = expf(-expf(Alog[n]));
    float h = Hin[((size_t)(b * DN + n)) * CH + c];
    const size_t base = ((size_t)(b * SEQL + c * LCH)) * DN + n;
#pragma unroll
    for (int t = 0; t < LCH; t++) {
        h = fmaf(a, h, Bu[base + (size_t)t * DN]);
        Ysb[base + (size_t)t * DN] = f2bf(Cc[base + (size_t)t * DN] * h);
    }
}

// ---------------------------------------------------------------------------
// GEMM3 (MFMA, K=64): T = Ys @ Ws2oT^T + D*u; in-place bf16 over Ub -> Tb.
// 128x128 tile, 2 K-steps of 32.
// ---------------------------------------------------------------------------
__global__ __launch_bounds__(256) void k_mfma_s2o(
    const u16* __restrict__ A, const u16* __restrict__ Bt,
    const float* __restrict__ Dv, u16* __restrict__ UT)
{
    constexpr int BK = 32;
    __shared__ u16 As[128 * BK];
    __shared__ u16 Bs[128 * BK];
    const int tid  = threadIdx.x;
    const int lane = tid & 63;
    const int w    = tid >> 6;
    const int wr   = w >> 1, wc = w & 1;
    const int m0   = blockIdx.y * 128;
    const int n0   = blockIdx.x * 128;

    f32x4 acc[4][4];
#pragma unroll
    for (int i = 0; i < 4; i++)
#pragma unroll
      for (int j = 0; j < 4; j++) acc[i][j] = (f32x4){0.f, 0.f, 0.f, 0.f};

    const int srow = tid >> 2;
    const int sk   = (tid & 3) * 8;
    const u16* aptr0 = A  + (size_t)(m0 + srow) * DN + sk;
    const u16* aptr1 = aptr0 + (size_t)64 * DN;
    const u16* bptr0 = Bt + (size_t)(n0 + srow) * DN + sk;
    const u16* bptr1 = bptr0 + (size_t)64 * DN;
    u16* asB0 = As + w * 512;
    u16* asB1 = As + 2048 + w * 512;
    u16* bsB0 = Bs + w * 512;
    u16* bsB1 = Bs + 2048 + w * 512;

    const int kg = lane >> 4;
    const int lr = lane & 15;
    const int aoff = (wr * 64 + lr) * BK + kg * 8;
    const int boff = (wc * 64 + lr) * BK + kg * 8;

#pragma unroll
    for (int k0 = 0; k0 < DN; k0 += BK) {
        gload_lds16(aptr0, asB0);
        gload_lds16(aptr1, asB1);
        gload_lds16(bptr0, bsB0);
        gload_lds16(bptr1, bsB1);
        aptr0 += BK; aptr1 += BK; bptr0 += BK; bptr1 += BK;
        __syncthreads();
        bf16x8 af[4], bfr[4];
#pragma unroll
        for (int i = 0; i < 4; i++)
            af[i]  = *reinterpret_cast<const bf16x8*>(&As[aoff + i * 16 * BK]);
#pragma unroll
        for (int j = 0; j < 4; j++)
            bfr[j] = *reinterpret_cast<const bf16x8*>(&Bs[boff + j * 16 * BK]);
#pragma unroll
        for (int i = 0; i < 4; i++)
#pragma unroll
          for (int j = 0; j < 4; j++)
            acc[i][j] = __builtin_amdgcn_mfma_f32_16x16x32_bf16(af[i], bfr[j], acc[i][j], 0, 0, 0);
        __syncthreads();
    }

#pragma unroll
    for (int j = 0; j < 4; j++) {
        const int col = n0 + wc * 64 + j * 16 + lr;
        const float dv = Dv[col];
#pragma unroll
        for (int i = 0; i < 4; i++) {
            const int rbase = m0 + wr * 64 + i * 16 + kg * 4;
#pragma unroll
            for (int r = 0; r < 4; r++) {
                const size_t idx = (size_t)(rbase + r) * DM + col;
                const float u = bf2f(UT[idx]);
                UT[idx] = f2bf(acc[i][j][r] + dv * u);
            }
        }
    }
}

// ---------------------------------------------------------------------------
extern "C" void kernel_launch(void* const* d_in, const int* in_sizes, int n_in,
                              void* d_out, int out_size, void* d_ws, size_t ws_size,
                              hipStream_t stream) {
    const float* X     = (const float*)d_in[0];
    const float* gamma = (const float*)d_in[1];
    const float* beta  = (const float*)d_in[2];
    const float* W_in  = (const float*)d_in[3];
    const float* b_in  = (const float*)d_in[4];
    const float* W_xs  = (const float*)d_in[5];
    const float* W_B   = (const float*)d_in[6];
    const float* b_B   = (const float*)d_in[7];
    const float* W_C   = (const float*)d_in[8];
    const float* b_C   = (const float*)d_in[9];
    const float* A_log = (const float*)d_in[10];
    const float* Dv    = (const float*)d_in[11];
    const float* W_s2o = (const float*)d_in[12];
    const float* W_out = (const float*)d_in[13];
    const float* b_out = (const float*)d_in[14];
    float* out = (float*)d_out;

    const int M = in_sizes[0] / DM;     // 32768 rows (B*S)
    const int B = M / SEQL;             // 8

    // Workspace layout (~86 MB)
    float* ws  = (float*)d_ws;
    float* Bu  = ws;                               // M*DN f32
    float* Cc  = Bu + (size_t)M * DN;              // M*DN f32
    float* Hl  = Cc + (size_t)M * DN;              // B*DN*CH
    float* Hin = Hl + (size_t)B * DN * CH;         // B*DN*CH
    u16* Xn    = (u16*)(Hin + (size_t)B * DN * CH); // M*DM bf16
    u16* Ub    = Xn + (size_t)M * DM;               // M*DM bf16 (alias Tb)
    u16* Ysb   = Ub + (size_t)M * DM;               // M*DN bf16
    u16* WinT  = Ysb + (size_t)M * DN;              // 512*512
    u16* WoutT = WinT + (size_t)DM * DM;            // 512*512
    u16* WbcxT = WoutT + (size_t)DM * DM;           // 192*512
    u16* Ws2oT = WbcxT + (size_t)3 * DN * DM;       // 512*64

    k_ln<<<M / 4, 256, 0, stream>>>(X, gamma, beta, Xn);
    k_wtransG<<<dim3(8, 8), 256, 0, stream>>>(W_in,  WinT,  DM, DM);
    k_wtransG<<<dim3(8, 8), 256, 0, stream>>>(W_out, WoutT, DM, DM);
    k_wtransG<<<dim3(1, 8), 256, 0, stream>>>(W_xs, WbcxT,            DM, DN);
    k_wtransG<<<dim3(1, 8), 256, 0, stream>>>(W_B,  WbcxT + 64 * DM,  DM, DN);
    k_wtransG<<<dim3(1, 8), 256, 0, stream>>>(W_C,  WbcxT + 128 * DM, DM, DN);
    k_wtransG<<<dim3(8, 1), 256, 0, stream>>>(W_s2o, Ws2oT, DN, DM);

    k_mfma512<0><<<dim3(DM / 128, M / 128), 256, 0, stream>>>(Xn, WinT, b_in, nullptr, Ub);
    k_mfma_bcx<<<dim3(M / 64), 256, 0, stream>>>(Ub, WbcxT, b_B, b_C, Bu, Cc);
    k_scan1<<<dim3(CH, B), 64, 0, stream>>>(Bu, A_log, Hl);
    k_carry<<<1, B * DN, 0, stream>>>(Hl, A_log, Hin);
    k_scan2<<<dim3(CH, B), 64, 0, stream>>>(Bu, Cc, Hin, A_log, Ysb);
    k_mfma_s2o<<<dim3(DM / 128, M / 128), 256, 0, stream>>>(Ysb, Ws2oT, Dv, Ub);
    k_mfma512<1><<<dim3(DM / 128, M / 128), 256, 0, stream>>>(Ub, WoutT, b_out, X, out);
}

// Round 9
// 174.087 us; speedup vs baseline: 3.3675x; 1.0687x over previous
//
#include <hip/hip_runtime.h>
#include <cstddef>

typedef unsigned short u16;

// Problem constants
constexpr int DM   = 512;    // d_model
constexpr int DN   = 64;     // d_state
constexpr int SEQL = 4096;
constexpr int CH   = 128;            // chunks per sequence for parallel scan
constexpr int LCH  = SEQL / CH;      // 32 steps per chunk
constexpr int KC   = DM + DN;        // 576: fused K for [Ys|u] @ Wcat

typedef __attribute__((ext_vector_type(8))) short bf16x8;
typedef __attribute__((ext_vector_type(4))) float f32x4;

__device__ inline u16 f2bf(float f) {
    unsigned int u = __float_as_uint(f);
    unsigned int r = u + 0x7FFFu + ((u >> 16) & 1u);   // round-to-nearest-even
    return (u16)(r >> 16);
}
__device__ inline float bf2f(u16 h) {
    return __uint_as_float(((unsigned int)h) << 16);
}

__device__ inline void gload_lds16(const void* g, void* l) {
    __builtin_amdgcn_global_load_lds(
        (const __attribute__((address_space(1))) void*)g,
        (__attribute__((address_space(3))) void*)l, 16, 0, 0);
}

// ---------------------------------------------------------------------------
// LayerNorm -> bf16: one wave per row of 512, writes Xn bf16.
// ---------------------------------------------------------------------------
__global__ __launch_bounds__(256) void k_ln(const float* __restrict__ X,
                                            const float* __restrict__ gamma,
                                            const float* __restrict__ beta,
                                            u16* __restrict__ Xn) {
    const int lane = threadIdx.x & 63;
    const int w    = threadIdx.x >> 6;
    const size_t row = (size_t)blockIdx.x * 4 + w;
    const float* xr = X + row * DM;
    float4 v0 = *reinterpret_cast<const float4*>(&xr[lane * 8]);
    float4 v1 = *reinterpret_cast<const float4*>(&xr[lane * 8 + 4]);
    float s  = v0.x + v0.y + v0.z + v0.w + v1.x + v1.y + v1.z + v1.w;
    float s2 = v0.x*v0.x + v0.y*v0.y + v0.z*v0.z + v0.w*v0.w
             + v1.x*v1.x + v1.y*v1.y + v1.z*v1.z + v1.w*v1.w;
#pragma unroll
    for (int o = 32; o > 0; o >>= 1) {
        s  += __shfl_xor(s, o);
        s2 += __shfl_xor(s2, o);
    }
    const float mu = s * (1.0f / DM);
    const float rs = rsqrtf(s2 * (1.0f / DM) - mu * mu + 1e-3f);
    float4 g0 = *reinterpret_cast<const float4*>(&gamma[lane * 8]);
    float4 g1 = *reinterpret_cast<const float4*>(&gamma[lane * 8 + 4]);
    float4 b0 = *reinterpret_cast<const float4*>(&beta[lane * 8]);
    float4 b1 = *reinterpret_cast<const float4*>(&beta[lane * 8 + 4]);
    union { u16 h[8]; uint4 v; } pk;
    pk.h[0] = f2bf((v0.x - mu) * rs * g0.x + b0.x);
    pk.h[1] = f2bf((v0.y - mu) * rs * g0.y + b0.y);
    pk.h[2] = f2bf((v0.z - mu) * rs * g0.z + b0.z);
    pk.h[3] = f2bf((v0.w - mu) * rs * g0.w + b0.w);
    pk.h[4] = f2bf((v1.x - mu) * rs * g1.x + b1.x);
    pk.h[5] = f2bf((v1.y - mu) * rs * g1.y + b1.y);
    pk.h[6] = f2bf((v1.z - mu) * rs * g1.z + b1.z);
    pk.h[7] = f2bf((v1.w - mu) * rs * g1.w + b1.w);
    *reinterpret_cast<uint4*>(&Xn[row * DM + lane * 8]) = pk.v;
}

// ---------------------------------------------------------------------------
// Transpose+convert (+optional per-k scale): Wt[n*ldo + k] = bf16(s[k]*W[k*N+n])
// grid (N/64, K/64).
// ---------------------------------------------------------------------------
__global__ __launch_bounds__(256) void k_wtransS(const float* __restrict__ W,
                                                 u16* __restrict__ Wt,
                                                 int K, int N, int ldo,
                                                 const float* __restrict__ scale) {
    __shared__ float tile[64][65];
    const int bx = blockIdx.x, by = blockIdx.y;
    const int tx = threadIdx.x & 63, ty = threadIdx.x >> 6;
#pragma unroll
    for (int r = ty; r < 64; r += 4)
        tile[r][tx] = W[(size_t)(by * 64 + r) * N + bx * 64 + tx];
    __syncthreads();
    const float sc = scale ? scale[by * 64 + tx] : 1.0f;
#pragma unroll
    for (int r = ty; r < 64; r += 4)
        Wt[(size_t)(bx * 64 + r) * ldo + by * 64 + tx] = f2bf(sc * tile[tx][r]);
}

// ---------------------------------------------------------------------------
// Wc = W_s2o @ W_out (64x512, K=512), written transposed into Wcat[n*576 + k].
// grid (8 n-tiles, 16 k-groups), block 256 = 64 n x 4 k.
// ---------------------------------------------------------------------------
__global__ __launch_bounds__(256) void k_wcat(const float* __restrict__ Ws2o,
                                              const float* __restrict__ Wout,
                                              u16* __restrict__ Wcat) {
    const int tn = threadIdx.x & 63;
    const int tk = threadIdx.x >> 6;
    const int n  = blockIdx.x * 64 + tn;
    const int k  = blockIdx.y * 4 + tk;
    float s = 0.f;
#pragma unroll 8
    for (int j = 0; j < DM; ++j)
        s = fmaf(Ws2o[(size_t)k * DM + j], Wout[(size_t)j * DM + n], s);
    Wcat[(size_t)n * KC + k] = f2bf(s);
}

// ---------------------------------------------------------------------------
// GEMM1: Ub = bf16(Xn @ WinT^T + b_in). 128x128 tile, BK=32, 2-phase dbuf
// (STAGE next -> compute cur -> __syncthreads), XCD swizzle. grid (4, M/128).
// ---------------------------------------------------------------------------
__global__ __launch_bounds__(256) void k_g1(const u16* __restrict__ A,
                                            const u16* __restrict__ Bt,
                                            const float* __restrict__ bias,
                                            u16* __restrict__ Out)
{
    __shared__ u16 As[2][4096];
    __shared__ u16 Bs[2][4096];
    const int tid = threadIdx.x, lane = tid & 63, w = tid >> 6;
    const int wr = w >> 1, wc = w & 1;
    int lid = blockIdx.y * gridDim.x + blockIdx.x;
    const int cpx = (gridDim.x * gridDim.y) >> 3;
    lid = (lid & 7) * cpx + (lid >> 3);            // bijective XCD swizzle
    const int n0 = (lid & 3) * 128;
    const int m0 = (lid >> 2) * 128;

    const int srow = tid >> 2, sk = (tid & 3) * 8;
    const u16* aR = A  + (size_t)(m0 + srow) * DM + sk;
    const u16* bR = Bt + (size_t)(n0 + srow) * DM + sk;
    const int kg = lane >> 4, lr = lane & 15;
    const int aoff = (wr * 64 + lr) * 32 + kg * 8;
    const int boff = (wc * 64 + lr) * 32 + kg * 8;

    f32x4 acc[4][4];
#pragma unroll
    for (int i = 0; i < 4; i++)
#pragma unroll
      for (int j = 0; j < 4; j++) acc[i][j] = (f32x4){0.f, 0.f, 0.f, 0.f};

    auto STAGE = [&](int buf, int s) {
        const u16* a0 = aR + s * 32;
        const u16* b0 = bR + s * 32;
        gload_lds16(a0,           &As[buf][w * 512]);
        gload_lds16(a0 + 64 * DM, &As[buf][2048 + w * 512]);
        gload_lds16(b0,           &Bs[buf][w * 512]);
        gload_lds16(b0 + 64 * DM, &Bs[buf][2048 + w * 512]);
    };

    STAGE(0, 0);
    __syncthreads();
    for (int s = 0; s < 16; ++s) {
        const int cur = s & 1;
        if (s + 1 < 16) STAGE(cur ^ 1, s + 1);
        bf16x8 af[4], bfr[4];
#pragma unroll
        for (int i = 0; i < 4; i++)
            af[i]  = *reinterpret_cast<const bf16x8*>(&As[cur][aoff + i * 512]);
#pragma unroll
        for (int j = 0; j < 4; j++)
            bfr[j] = *reinterpret_cast<const bf16x8*>(&Bs[cur][boff + j * 512]);
#pragma unroll
        for (int i = 0; i < 4; i++)
#pragma unroll
          for (int j = 0; j < 4; j++)
            acc[i][j] = __builtin_amdgcn_mfma_f32_16x16x32_bf16(af[i], bfr[j], acc[i][j], 0, 0, 0);
        __syncthreads();
    }

#pragma unroll
    for (int j = 0; j < 4; j++) {
        const int col = n0 + wc * 64 + j * 16 + lr;
        const float bv = bias[col];
#pragma unroll
        for (int i = 0; i < 4; i++) {
            const int rbase = m0 + wr * 64 + i * 16 + kg * 4;
#pragma unroll
            for (int r = 0; r < 4; r++)
                Out[(size_t)(rbase + r) * DM + col] = f2bf(acc[i][j][r] + bv);
        }
    }
}

// ---------------------------------------------------------------------------
// GEMM2: [xs|Bm|Cm] = Ub @ WbcxT^T (192x512). BM=64 tile, 2-phase dbuf.
// Epilogue: Bu = (Bm+b_B)*xs, Cc = Cm+b_C.
// ---------------------------------------------------------------------------
__global__ __launch_bounds__(256) void k_mfma_bcx(
    const u16* __restrict__ A, const u16* __restrict__ Bt,
    const float* __restrict__ bB, const float* __restrict__ bC,
    float* __restrict__ Bu, float* __restrict__ Cc)
{
    __shared__ u16 As[2][2048];
    __shared__ u16 Bs[2][6144];
    const int tid = threadIdx.x, lane = tid & 63, w = tid >> 6;
    const int m0 = blockIdx.x * 64;

    f32x4 acc[12];
#pragma unroll
    for (int j = 0; j < 12; j++) acc[j] = (f32x4){0.f, 0.f, 0.f, 0.f};

    const int srow = tid >> 2, sk = (tid & 3) * 8;
    const u16* aR = A  + (size_t)(m0 + srow) * DM + sk;
    const u16* bR = Bt + (size_t)srow * DM + sk;
    const int kg = lane >> 4, lr = lane & 15;
    const int aoff = (w * 16 + lr) * 32 + kg * 8;

    auto STAGE = [&](int buf, int s) {
        const u16* a0 = aR + s * 32;
        const u16* b0 = bR + s * 32;
        gload_lds16(a0,            &As[buf][w * 512]);
        gload_lds16(b0,            &Bs[buf][w * 512]);
        gload_lds16(b0 + 64 * DM,  &Bs[buf][2048 + w * 512]);
        gload_lds16(b0 + 128 * DM, &Bs[buf][4096 + w * 512]);
    };

    STAGE(0, 0);
    __syncthreads();
    for (int s = 0; s < 16; ++s) {
        const int cur = s & 1;
        if (s + 1 < 16) STAGE(cur ^ 1, s + 1);
        bf16x8 af = *reinterpret_cast<const bf16x8*>(&As[cur][aoff]);
#pragma unroll
        for (int j = 0; j < 12; j++) {
            bf16x8 bfr = *reinterpret_cast<const bf16x8*>(&Bs[cur][(j * 16 + lr) * 32 + kg * 8]);
            acc[j] = __builtin_amdgcn_mfma_f32_16x16x32_bf16(af, bfr, acc[j], 0, 0, 0);
        }
        __syncthreads();
    }

#pragma unroll
    for (int j = 0; j < 4; j++) {
        const int col = j * 16 + lr;
        const float bBv = bB[col], bCv = bC[col];
#pragma unroll
        for (int r = 0; r < 4; r++) {
            const int grow = m0 + w * 16 + kg * 4 + r;
            const float xs = acc[j][r];
            const float bm = acc[j + 4][r] + bBv;
            const float cm = acc[j + 8][r] + bCv;
            Bu[(size_t)grow * DN + col] = bm * xs;
            Cc[(size_t)grow * DN + col] = cm;
        }
    }
}

// ---------------------------------------------------------------------------
// Chunked parallel scan (exact): h[t] = a*h[t-1] + Bu[t], a const per channel.
// ---------------------------------------------------------------------------
__global__ void k_scan1(const float* __restrict__ Bu, const float* __restrict__ Alog,
                        float* __restrict__ Hl) {
    const int n = threadIdx.x;
    const int c = blockIdx.x;
    const int b = blockIdx.y;
    const float a = expf(-expf(Alog[n]));
    const float* p = Bu + ((size_t)(b * SEQL + c * LCH)) * DN + n;
    float h = 0.f;
#pragma unroll
    for (int t = 0; t < LCH; t++) h = fmaf(a, h, p[(size_t)t * DN]);
    Hl[(b * DN + n) * CH + c] = h;
}

__global__ void k_carry(const float* __restrict__ Hl, const float* __restrict__ Alog,
                        float* __restrict__ Hin) {
    const int i = threadIdx.x;        // b*64 + n
    const int n = i & 63;
    const float a  = expf(-expf(Alog[n]));
    const float aL = powf(a, (float)LCH);
    float hend = 0.f;
    for (int c = 0; c < CH; c++) {
        Hin[(size_t)i * CH + c] = hend;
        hend = fmaf(aL, hend, Hl[(size_t)i * CH + c]);
    }
}

__global__ void k_scan2(const float* __restrict__ Bu, const float* __restrict__ Cc,
                        const float* __restrict__ Hin, const float* __restrict__ Alog,
                        u16* __restrict__ Ysb) {
    const int n = threadIdx.x;
    const int c = blockIdx.x;
    const int b = blockIdx.y;
    const float a = expf(-expf(Alog[n]));
    float h = Hin[((size_t)(b * DN + n)) * CH + c];
    const size_t base = ((size_t)(b * SEQL + c * LCH)) * DN + n;
#pragma unroll
    for (int t = 0; t < LCH; t++) {
        h = fmaf(a, h, Bu[base + (size_t)t * DN]);
        Ysb[base + (size_t)t * DN] = f2bf(Cc[base + (size_t)t * DN] * h);
    }
}

// ---------------------------------------------------------------------------
// Fused GEMM3+4: out = [Ys | u] @ Wcat^T + b_out + X.  K = 576.
// Wcat[n][k]: k<64 -> (W_s2o@W_out)[k,n]; k>=64 -> D[k-64]*W_out[k-64,n].
// 128x128 tile, 2-phase dbuf, XCD swizzle. grid (4, M/128).
// ---------------------------------------------------------------------------
__global__ __launch_bounds__(256) void k_gfuse(
    const u16* __restrict__ Ysb, const u16* __restrict__ Ub,
    const u16* __restrict__ Wcat, const float* __restrict__ bias,
    const float* __restrict__ X, float* __restrict__ Out)
{
    __shared__ u16 As[2][4096];
    __shared__ u16 Bs[2][4096];
    const int tid = threadIdx.x, lane = tid & 63, w = tid >> 6;
    const int wr = w >> 1, wc = w & 1;
    int lid = blockIdx.y * gridDim.x + blockIdx.x;
    const int cpx = (gridDim.x * gridDim.y) >> 3;
    lid = (lid & 7) * cpx + (lid >> 3);
    const int n0 = (lid & 3) * 128;
    const int m0 = (lid >> 2) * 128;

    const int srow = tid >> 2, sk = (tid & 3) * 8;
    const u16* aY = Ysb + (size_t)(m0 + srow) * DN + sk;
    const u16* aU = Ub  + (size_t)(m0 + srow) * DM + sk;
    const u16* bR = Wcat + (size_t)(n0 + srow) * KC + sk;
    const int kg = lane >> 4, lr = lane & 15;
    const int aoff = (wr * 64 + lr) * 32 + kg * 8;
    const int boff = (wc * 64 + lr) * 32 + kg * 8;

    f32x4 acc[4][4];
#pragma unroll
    for (int i = 0; i < 4; i++)
#pragma unroll
      for (int j = 0; j < 4; j++) acc[i][j] = (f32x4){0.f, 0.f, 0.f, 0.f};

    auto STAGE = [&](int buf, int s) {
        const u16 *a0, *a1;
        if (s < 2) { a0 = aY + s * 32;       a1 = a0 + 64 * DN; }
        else       { a0 = aU + (s - 2) * 32; a1 = a0 + 64 * DM; }
        const u16* b0 = bR + s * 32;
        gload_lds16(a0,           &As[buf][w * 512]);
        gload_lds16(a1,           &As[buf][2048 + w * 512]);
        gload_lds16(b0,           &Bs[buf][w * 512]);
        gload_lds16(b0 + 64 * KC, &Bs[buf][2048 + w * 512]);
    };

    STAGE(0, 0);
    __syncthreads();
    for (int s = 0; s < 18; ++s) {
        const int cur = s & 1;
        if (s + 1 < 18) STAGE(cur ^ 1, s + 1);
        bf16x8 af[4], bfr[4];
#pragma unroll
        for (int i = 0; i < 4; i++)
            af[i]  = *reinterpret_cast<const bf16x8*>(&As[cur][aoff + i * 512]);
#pragma unroll
        for (int j = 0; j < 4; j++)
            bfr[j] = *reinterpret_cast<const bf16x8*>(&Bs[cur][boff + j * 512]);
#pragma unroll
        for (int i = 0; i < 4; i++)
#pragma unroll
          for (int j = 0; j < 4; j++)
            acc[i][j] = __builtin_amdgcn_mfma_f32_16x16x32_bf16(af[i], bfr[j], acc[i][j], 0, 0, 0);
        __syncthreads();
    }

#pragma unroll
    for (int j = 0; j < 4; j++) {
        const int col = n0 + wc * 64 + j * 16 + lr;
        const float bv = bias[col];
#pragma unroll
        for (int i = 0; i < 4; i++) {
            const int rbase = m0 + wr * 64 + i * 16 + kg * 4;
#pragma unroll
            for (int r = 0; r < 4; r++) {
                const size_t idx = (size_t)(rbase + r) * DM + col;
                Out[idx] = acc[i][j][r] + bv + X[idx];
            }
        }
    }
}

// ---------------------------------------------------------------------------
extern "C" void kernel_launch(void* const* d_in, const int* in_sizes, int n_in,
                              void* d_out, int out_size, void* d_ws, size_t ws_size,
                              hipStream_t stream) {
    const float* X     = (const float*)d_in[0];
    const float* gamma = (const float*)d_in[1];
    const float* beta  = (const float*)d_in[2];
    const float* W_in  = (const float*)d_in[3];
    const float* b_in  = (const float*)d_in[4];
    const float* W_xs  = (const float*)d_in[5];
    const float* W_B   = (const float*)d_in[6];
    const float* b_B   = (const float*)d_in[7];
    const float* W_C   = (const float*)d_in[8];
    const float* b_C   = (const float*)d_in[9];
    const float* A_log = (const float*)d_in[10];
    const float* Dv    = (const float*)d_in[11];
    const float* W_s2o = (const float*)d_in[12];
    const float* W_out = (const float*)d_in[13];
    const float* b_out = (const float*)d_in[14];
    float* out = (float*)d_out;

    const int M = in_sizes[0] / DM;     // 32768 rows (B*S)
    const int B = M / SEQL;             // 8

    // Workspace layout (~90 MB)
    float* ws  = (float*)d_ws;
    float* Bu  = ws;                                // M*DN f32
    float* Cc  = Bu + (size_t)M * DN;               // M*DN f32
    float* Hl  = Cc + (size_t)M * DN;               // B*DN*CH
    float* Hin = Hl + (size_t)B * DN * CH;          // B*DN*CH
    u16* Xn    = (u16*)(Hin + (size_t)B * DN * CH); // M*DM bf16
    u16* Ub    = Xn + (size_t)M * DM;               // M*DM bf16
    u16* Ysb   = Ub + (size_t)M * DM;               // M*DN bf16
    u16* WinT  = Ysb + (size_t)M * DN;              // 512*512
    u16* WbcxT = WinT + (size_t)DM * DM;            // 192*512
    u16* WcatT = WbcxT + (size_t)3 * DN * DM;       // 512*576

    k_ln<<<M / 4, 256, 0, stream>>>(X, gamma, beta, Xn);
    k_wtransS<<<dim3(8, 8), 256, 0, stream>>>(W_in, WinT, DM, DM, DM, nullptr);
    k_wtransS<<<dim3(1, 8), 256, 0, stream>>>(W_xs, WbcxT,            DM, DN, DM, nullptr);
    k_wtransS<<<dim3(1, 8), 256, 0, stream>>>(W_B,  WbcxT + 64 * DM,  DM, DN, DM, nullptr);
    k_wtransS<<<dim3(1, 8), 256, 0, stream>>>(W_C,  WbcxT + 128 * DM, DM, DN, DM, nullptr);
    k_wtransS<<<dim3(8, 8), 256, 0, stream>>>(W_out, WcatT + 64, DM, DM, KC, Dv);
    k_wcat<<<dim3(8, 16), 256, 0, stream>>>(W_s2o, W_out, WcatT);

    k_g1<<<dim3(4, M / 128), 256, 0, stream>>>(Xn, WinT, b_in, Ub);
    k_mfma_bcx<<<dim3(M / 64), 256, 0, stream>>>(Ub, WbcxT, b_B, b_C, Bu, Cc);
    k_scan1<<<dim3(CH, B), 64, 0, stream>>>(Bu, A_log, Hl);
    k_carry<<<1, B * DN, 0, stream>>>(Hl, A_log, Hin);
    k_scan2<<<dim3(CH, B), 64, 0, stream>>>(Bu, Cc, Hin, A_log, Ysb);
    k_gfuse<<<dim3(4, M / 128), 256, 0, stream>>>(Ysb, Ub, WcatT, b_out, X, out);
}